// Round 1
// 16160.080 us; speedup vs baseline: 1.2759x; 1.2759x over previous
//
#include <hip/hip_runtime.h>
#include <cstdint>
#include <cstddef>

// Problem dims
#define TT   1024
#define BB   128
#define FEAT 138
#define FPAD 160            // x K-pad (20 chunks of 8)
#define HH   1024
#define VV   128
#define MM   128
#define K1   1184           // FPAD + HH
#define K1P  1280           // padded to 40 k-tiles of 32 (tiles 37..39 zero-A)
#define K2   2048           // 64 k-tiles
#define HCH  1024           // u16 per k-chunk of h-like buffers: 128 b x 8 k
#define H1N  131072         // u16 per h buffer (128 chunks)
#define MIDN 16384          // u16 per mid buffer (16 chunks)
#define PKM1 1032           // LDS row stride, MLP W1 slice
#define PKM2 136            // LDS row stride, MLP W2 slice
// LDS layout (bytes)
#define OFF_RED 0           // 32 KB: split-k reduction staging (4 regions x 8 KB)
#define OFF_WM  32768       // 33 KB: MLP weight slice
#define OFF_H   65792       // 2 KB: h epilogue transpose staging (2 x 1 KB)
#define OFF_M   67840       // 1 KB: MLP epilogue staging
#define LDSZ    68864

typedef __bf16 bf16x8 __attribute__((ext_vector_type(8)));
typedef float  f32x4  __attribute__((ext_vector_type(4)));
typedef unsigned short u16;

__device__ __forceinline__ u16 f2bf(float f) {  // RNE float->bf16
  uint32_t u = __float_as_uint(f);
  u += 0x7fffu + ((u >> 16) & 1u);
  return (u16)(u >> 16);
}
__device__ __forceinline__ float sigm(float x) { return 1.0f / (1.0f + __expf(-x)); }
__device__ __forceinline__ float tanh_(float x) {
  float e = __expf(-2.0f * fabsf(x));
  float t = (1.0f - e) / (1.0f + e);
  return x < 0.0f ? -t : t;
}

// ---- fence-free cross-XCD coherent access (sc0 sc1: bypass L1+L2, hit L3) ----
// Relaxed agent-scope atomics lower to global_load/store_dwordx2 sc0 sc1 with
// compiler-managed waitcnt. No buffer_wbl2 / buffer_inv anywhere.
__device__ __forceinline__ bf16x8 ldcc8(const u16* p) {
  union { unsigned long long q[2]; bf16x8 v; } u;
  const unsigned long long* p64 = (const unsigned long long*)p;
  u.q[0] = __hip_atomic_load(p64,     __ATOMIC_RELAXED, __HIP_MEMORY_SCOPE_AGENT);
  u.q[1] = __hip_atomic_load(p64 + 1, __ATOMIC_RELAXED, __HIP_MEMORY_SCOPE_AGENT);
  return u.v;
}
__device__ __forceinline__ void stcc16(u16* p, uint4 v) {
  unsigned long long* p64 = (unsigned long long*)p;
  unsigned long long lo = ((unsigned long long)v.y << 32) | v.x;
  unsigned long long hi = ((unsigned long long)v.w << 32) | v.z;
  __hip_atomic_store(p64,     lo, __ATOMIC_RELAXED, __HIP_MEMORY_SCOPE_AGENT);
  __hip_atomic_store(p64 + 1, hi, __ATOMIC_RELAXED, __HIP_MEMORY_SCOPE_AGENT);
}

// ---------------- prep kernels ----------------
// Gate-interleaved rows r' = hc*4 + gate, K-major; W1 padded to K1P with zeros.
__global__ void conv_w1i(const float* __restrict__ Wih, const float* __restrict__ Whh,
                         const float* __restrict__ bi, const float* __restrict__ bh,
                         u16* __restrict__ dst, float* __restrict__ bsum) {
  int rp = blockIdx.x;                 // 4096
  int hc = rp >> 2, g = rp & 3;
  int sr = g * HH + hc;
  if (threadIdx.x == 0) bsum[rp] = bi[sr] + bh[sr];
  for (int k = threadIdx.x; k < K1P; k += 256) {
    float v = 0.0f;
    if (k < FPAD)    v = (k < FEAT) ? Wih[(size_t)sr * FEAT + k] : 0.0f;
    else if (k < K1) v = Whh[(size_t)sr * HH + (k - FPAD)];
    dst[(size_t)rp * K1P + k] = f2bf(v);
  }
}
__global__ void conv_w2i(const float* __restrict__ Wih, const float* __restrict__ Whh,
                         const float* __restrict__ bi, const float* __restrict__ bh,
                         u16* __restrict__ dst, float* __restrict__ bsum) {
  int rp = blockIdx.x;
  int hc = rp >> 2, g = rp & 3;
  int sr = g * HH + hc;
  if (threadIdx.x == 0) bsum[rp] = bi[sr] + bh[sr];
  for (int k = threadIdx.x; k < K2; k += 256) {
    float v = (k < HH) ? Wih[(size_t)sr * HH + k] : Whh[(size_t)sr * HH + (k - HH)];
    dst[(size_t)rp * K2 + k] = f2bf(v);
  }
}
__global__ void conv_mlpw(const float* __restrict__ W1, const float* __restrict__ W2,
                          u16* __restrict__ A, u16* __restrict__ Bm) {
  int i = blockIdx.x * 256 + threadIdx.x;          // 576*256 covers 131072+16384
  if (i < MM * HH) A[i] = f2bf(W1[i]);
  else {
    int j = i - MM * HH;
    if (j < VV * MM) Bm[j] = f2bf(W2[j]);
  }
}
// x -> chunked bf16 [t][20 c][128 b][8 k]
__global__ void conv_x(const float* __restrict__ x, u16* __restrict__ Xb) {
  int blk = blockIdx.x;                 // TT*20
  int t = blk / 20, c = blk % 20;
  int b = threadIdx.x;
  if (b >= BB) return;
  const float* src = x + ((size_t)t * BB + b) * FEAT;
  u16 v[8];
#pragma unroll
  for (int e = 0; e < 8; ++e) {
    int col = c * 8 + e;
    v[e] = (col < FEAT) ? f2bf(src[col]) : (u16)0;
  }
  *(uint4*)(Xb + (((size_t)t * 20 + c) * BB + b) * 8) = *(uint4*)v;
}
__global__ void zero_ws(uint4* __restrict__ p, int n16) {
  int i = blockIdx.x * 256 + threadIdx.x;
  if (i < n16) p[i] = uint4{0, 0, 0, 0};
}

// ---------------- fused persistent kernel helpers ----------------

// x-tile path: normal (cached) loads — Xb is written once pre-launch.
__device__ __forceinline__ void mac_step(const bf16x8& a0, const bf16x8& a1,
                                         const u16* __restrict__ bptr,
                                         f32x4 (&acc)[2][4]) {
  bf16x8 Bf[4];
#pragma unroll
  for (int n = 0; n < 4; ++n) Bf[n] = *(const bf16x8*)(bptr + n * 128);
#pragma unroll
  for (int n = 0; n < 4; ++n) {
    acc[0][n] = __builtin_amdgcn_mfma_f32_16x16x32_bf16(a0, Bf[n], acc[0][n], 0, 0, 0);
    acc[1][n] = __builtin_amdgcn_mfma_f32_16x16x32_bf16(a1, Bf[n], acc[1][n], 0, 0, 0);
  }
}

__device__ __forceinline__ void ld_tile_cc(const u16* bptr, bf16x8 (&B)[4]) {
#pragma unroll
  for (int n = 0; n < 4; ++n) B[n] = ldcc8(bptr + n * 128);
}
__device__ __forceinline__ void mfma_tile(const bf16x8& a0, const bf16x8& a1,
                                          const bf16x8 (&B)[4], f32x4 (&acc)[2][4]) {
#pragma unroll
  for (int n = 0; n < 4; ++n) {
    acc[0][n] = __builtin_amdgcn_mfma_f32_16x16x32_bf16(a0, B[n], acc[0][n], 0, 0, 0);
    acc[1][n] = __builtin_amdgcn_mfma_f32_16x16x32_bf16(a1, B[n], acc[1][n], 0, 0, 0);
  }
}
// Depth-4 software-pipelined k-tile ring over coherent-bypass loads.
// Static indexing only (s % D with unrolled s) — keeps Bq in registers.
template<int NT, int OFS, int NA>
__device__ __forceinline__ void mac_ring_cc(const bf16x8 (&A0)[NA], const bf16x8 (&A1)[NA],
                                            const u16* __restrict__ bp,
                                            f32x4 (&acc)[2][4]) {
  constexpr int D = NT < 4 ? NT : 4;
  bf16x8 Bq[D][4];
#pragma unroll
  for (int s = 0; s < D; ++s) ld_tile_cc(bp + (size_t)s * 4096, Bq[s]);
#pragma unroll
  for (int s = 0; s < NT; ++s) {
    mfma_tile(A0[OFS + s], A1[OFS + s], Bq[s % D], acc);
    if (s + D < NT) ld_tile_cc(bp + (size_t)(s + D) * 4096, Bq[s % D]);
  }
}

__device__ __forceinline__ void red_write(float* __restrict__ rg,
                                          const f32x4 (&acc)[2][4], int lane) {
#pragma unroll
  for (int mt = 0; mt < 2; ++mt)
#pragma unroll
    for (int n = 0; n < 4; ++n)
      *(f32x4*)(rg + (mt * 4 + n) * 256 + lane * 4) = acc[mt][n];
}
__device__ __forceinline__ void red_add(const float* __restrict__ rg,
                                        f32x4 (&acc)[2][4], int lane) {
#pragma unroll
  for (int mt = 0; mt < 2; ++mt)
#pragma unroll
    for (int n = 0; n < 4; ++n)
      acc[mt][n] += *(const f32x4*)(rg + (mt * 4 + n) * 256 + lane * 4);
}

// kw0 epilogue: gates -> c,h (registers), LDS transpose, coalesced h chunk write.
__device__ __forceinline__ void lstm_tail(f32x4 (&acc)[2][4], const f32x4& bsv0,
                                          const f32x4& bsv1, float (&cst)[2][4],
                                          char* smem, int bh, int lane, int q, int l16,
                                          u16* __restrict__ houtChunk) {
  u16* st = (u16*)(smem + OFF_H) + bh * 512;
#pragma unroll
  for (int mt = 0; mt < 2; ++mt) {
    const f32x4 bsv = mt ? bsv1 : bsv0;
#pragma unroll
    for (int n = 0; n < 4; ++n) {
      float iv = sigm(acc[mt][n][0] + bsv[0]);
      float fv = sigm(acc[mt][n][1] + bsv[1]);
      float gv = tanh_(acc[mt][n][2] + bsv[2]);
      float ov = sigm(acc[mt][n][3] + bsv[3]);
      float c = fv * cst[mt][n] + iv * gv;
      cst[mt][n] = c;
      st[(n * 16 + l16) * 8 + mt * 4 + q] = f2bf(ov * tanh_(c));
    }
  }
  uint4 hv4 = *(uint4*)((u16*)(smem + OFF_H) + bh * 512 + lane * 8);
  stcc16(houtChunk + ((size_t)bh * 64 + lane) * 8, hv4);   // write-through past L2
}

// Grid barrier: NO agent fences. Release = per-wave vmcnt(0) drain (all
// cross-block stores are sc0sc1 write-through, so nothing dirty in L2).
// Acquire = nothing (all cross-block loads are sc0sc1 L2-bypass).
__device__ __forceinline__ void gbar(unsigned* __restrict__ bar, unsigned g) {
  asm volatile("s_waitcnt vmcnt(0)" ::: "memory");  // release: stores acked at L3
  __syncthreads();
  if (threadIdx.x == 0) {
    unsigned v = __hip_atomic_fetch_add(&bar[(blockIdx.x & 7) * 16], 1u,
                                        __ATOMIC_RELAXED, __HIP_MEMORY_SCOPE_AGENT);
    if (v == 32u * g - 1u) {
      unsigned w = __hip_atomic_fetch_add(&bar[128], 1u,
                                          __ATOMIC_RELAXED, __HIP_MEMORY_SCOPE_AGENT);
      if (w == 8u * g - 1u)
        __hip_atomic_store(&bar[144], g, __ATOMIC_RELAXED, __HIP_MEMORY_SCOPE_AGENT);
    }
    while (__hip_atomic_load(&bar[144], __ATOMIC_RELAXED,
                             __HIP_MEMORY_SCOPE_AGENT) < g)
      __builtin_amdgcn_s_sleep(8);
  }
  __syncthreads();
}

// 256 blocks x 512 thr. Blocks [0,128): LSTM1 slice j (+ MLP); [128,256): LSTM2.
// Waves: w = bh*4 + kw; kw = k-split (4-way), bh = batch-half (2-way).
// Weights register-resident; split-k partials reduced via LDS tree (2 rounds).
__global__ __launch_bounds__(512, 2) void fused_lstm(
    const u16* __restrict__ W1i, const u16* __restrict__ W2i,
    const u16* __restrict__ W1m, const u16* __restrict__ W2m,
    const u16* __restrict__ Xb, u16* __restrict__ h1b, u16* __restrict__ h2b,
    u16* __restrict__ midb,
    const float* __restrict__ bs1, const float* __restrict__ bs2,
    const float* __restrict__ bm1, const float* __restrict__ bm2,
    float* __restrict__ out, unsigned* __restrict__ bar)
{
  extern __shared__ char smem[];
  const int tid = threadIdx.x, bid = blockIdx.x;
  const int w = tid >> 6, lane = tid & 63, q = lane >> 4, l16 = lane & 15;
  const int kw = w & 3, bh = w >> 2;
  const bool isL1 = bid < 128;
  const int j = isL1 ? bid : bid - 128;          // hc-slice: hc = j*8 .. j*8+8
  float* red = (float*)(smem + OFF_RED);
  u16* Wm = (u16*)(smem + OFF_WM);

  float cst[2][4] = {{0, 0, 0, 0}, {0, 0, 0, 0}};   // kw0: persistent cell state
  f32x4 bsv0 = {0, 0, 0, 0}, bsv1 = {0, 0, 0, 0};
  if (kw == 0) {
    const float* bs = isL1 ? bs1 : bs2;
    bsv0 = *(const f32x4*)(bs + (j * 8 + q) * 4);
    bsv1 = *(const f32x4*)(bs + (j * 8 + 4 + q) * 4);
  }

  if (isL1) {
    // ---- register-resident A: 2 m-tiles x 10 k-tiles (tiles kw*10..kw*10+9) ----
    bf16x8 A1[2][10];
#pragma unroll
    for (int mt = 0; mt < 2; ++mt)
#pragma unroll
      for (int s = 0; s < 10; ++s)
        A1[mt][s] = *(const bf16x8*)(W1i + (size_t)(j * 32 + mt * 16 + l16) * K1P +
                                     (size_t)(kw * 10 + s) * 32 + q * 8);
    // MLP weight slice -> LDS
    if (j < 64) {
      int m0 = (j & 7) * 16;
      for (int i = tid; i < 16 * 128; i += 512) {
        int r = i >> 7, c8 = i & 127;
        *(uint4*)(Wm + r * PKM1 + c8 * 8) =
            *(const uint4*)(W1m + ((size_t)(m0 + r)) * HH + c8 * 8);
      }
    } else {
      int v0 = ((j - 64) & 7) * 16;
      for (int i = tid; i < 16 * 16; i += 512) {
        int r = i >> 4, c8 = i & 15;
        *(uint4*)(Wm + r * PKM2 + c8 * 8) =
            *(const uint4*)(W2m + ((size_t)(v0 + r)) * MM + c8 * 8);
      }
    }
    f32x4 bmv = {0, 0, 0, 0};
    if (w == 3) {
      if (j < 64) bmv = *(const f32x4*)(bm1 + (j & 7) * 16 + q * 4);
      else        bmv = *(const f32x4*)(bm2 + ((j - 64) & 7) * 16 + q * 4);
    }
    __syncthreads();

    for (int p = 0; p < TT + 3; ++p) {
      const bool act = p < TT;
      if (act) {                        // ---- LSTM1, t = p ----
        const u16* h1p = h1b + (size_t)((p - 1) & 1) * H1N;
        f32x4 acc[2][4];
#pragma unroll
        for (int mt = 0; mt < 2; ++mt)
#pragma unroll
          for (int n = 0; n < 4; ++n) acc[mt][n] = (f32x4){0, 0, 0, 0};
        if (kw == 0) {                  // tiles 0..4 from x, 5..9 from h1prev
          const u16* bx = Xb + (size_t)p * 20480 +
                          ((size_t)q * 128 + bh * 64 + l16) * 8;
#pragma unroll
          for (int s = 0; s < 5; ++s)
            mac_step(A1[0][s], A1[1][s], bx + (size_t)s * 4096, acc);
          const u16* bp = h1p + ((size_t)q * 128 + bh * 64 + l16) * 8;
          mac_ring_cc<5, 5, 10>(A1[0], A1[1], bp, acc);
        } else {                        // tiles kw*10.. from h1prev (lt0 = kw*10-5)
          const u16* bp = h1p + ((size_t)((kw * 10 - 5) * 4 + q) * 128 +
                                 bh * 64 + l16) * 8;
          mac_ring_cc<10, 0, 10>(A1[0], A1[1], bp, acc);
        }
        // split-k tree reduction
        if (kw >= 2) red_write(red + (bh * 2 + kw - 2) * 2048, acc, lane);
        __syncthreads();
        if (kw < 2)  red_add(red + (bh * 2 + kw) * 2048, acc, lane);
        if (kw == 1) red_write(red + (bh * 2 + 1) * 2048, acc, lane);
        __syncthreads();
        if (kw == 0) {
          red_add(red + (bh * 2 + 1) * 2048, acc, lane);
          lstm_tail(acc, bsv0, bsv1, cst, smem, bh, lane, q, l16,
                    h1b + (size_t)(p & 1) * H1N + (size_t)j * HCH);
        }
      }
      if (w == 3) {                     // ---- MLP (wave 3 of L1 blocks) ----
        if (j < 64) {
          if (p >= 2 && p <= TT + 1) {  // mid, t = p-2
            int jm = j & 7, jb = j >> 3;
            const u16* bsrc = h2b + (size_t)(p & 1) * H1N + q * HCH +
                              (jb * 16 + l16) * 8;
            const u16* am = Wm + l16 * PKM1 + q * 8;
            f32x4 acc = {0, 0, 0, 0};
            bf16x8 Bq[8];
#pragma unroll
            for (int s = 0; s < 8; ++s) Bq[s] = ldcc8(bsrc + (size_t)s * 4096);
#pragma unroll
            for (int s = 0; s < 32; ++s) {
              bf16x8 af = *(const bf16x8*)(am + s * 32);
              acc = __builtin_amdgcn_mfma_f32_16x16x32_bf16(af, Bq[s % 8], acc, 0, 0, 0);
              if (s + 8 < 32) Bq[s % 8] = ldcc8(bsrc + (size_t)(s + 8) * 4096);
            }
            const float SC = 1.0507009873554804934193349852946f;
            const float AL = 1.6732632423543772848170429916717f;
            u16* st16 = (u16*)(smem + OFF_M);
#pragma unroll
            for (int r = 0; r < 4; ++r) {
              float v = acc[r] + bmv[r];
              v = v > 0.0f ? SC * v : SC * AL * (__expf(v) - 1.0f);
              st16[l16 * 16 + q * 4 + r] = f2bf(v);
            }
            if (lane < 16) {
              uint4 v0 = *(uint4*)(st16 + lane * 16);
              uint4 v1 = *(uint4*)(st16 + lane * 16 + 8);
              u16* mc = midb + (size_t)(p & 1) * MIDN;
              stcc16(mc + (size_t)(2 * jm) * HCH + (jb * 16 + lane) * 8, v0);
              stcc16(mc + (size_t)(2 * jm + 1) * HCH + (jb * 16 + lane) * 8, v1);
            }
          }
        } else if (p >= 3) {            // out, t = p-3
          int jj = j - 64, jv = jj & 7, jb = jj >> 3;
          const u16* bsrc = midb + (size_t)((p - 3) & 1) * MIDN + q * HCH +
                            (jb * 16 + l16) * 8;
          const u16* am = Wm + l16 * PKM2 + q * 8;
          f32x4 acc = {0, 0, 0, 0};
          bf16x8 Bq[4];
#pragma unroll
          for (int s = 0; s < 4; ++s) Bq[s] = ldcc8(bsrc + (size_t)s * 4096);
#pragma unroll
          for (int s = 0; s < 4; ++s) {
            bf16x8 af = *(const bf16x8*)(am + s * 32);
            acc = __builtin_amdgcn_mfma_f32_16x16x32_bf16(af, Bq[s], acc, 0, 0, 0);
          }
          float* stf = (float*)(smem + OFF_M);
#pragma unroll
          for (int r = 0; r < 4; ++r) stf[l16 * 16 + q * 4 + r] = acc[r] + bmv[r];
          if (lane < 16) {
            float* orow = out + ((size_t)(p - 3) * BB + jb * 16 + lane) * VV + jv * 16;
            uint4* s4 = (uint4*)(stf + lane * 16);
            *(uint4*)(orow + 0)  = s4[0];
            *(uint4*)(orow + 4)  = s4[1];
            *(uint4*)(orow + 8)  = s4[2];
            *(uint4*)(orow + 12) = s4[3];
          }
        }
      }
      gbar(bar, (unsigned)p + 1u);
    }
  } else {
    // ---- LSTM2: register A: 2 m-tiles x 16 k-tiles (tiles kw*16..kw*16+15) ----
    bf16x8 A2[2][16];
#pragma unroll
    for (int mt = 0; mt < 2; ++mt)
#pragma unroll
      for (int s = 0; s < 16; ++s)
        A2[mt][s] = *(const bf16x8*)(W2i + (size_t)(j * 32 + mt * 16 + l16) * K2 +
                                     (size_t)(kw * 16 + s) * 32 + q * 8);

    for (int p = 0; p < TT + 3; ++p) {
      const bool act = (p >= 1 && p <= TT);
      if (act) {                        // ---- LSTM2, t = p-1 ----
        const int t = p - 1;
        const u16* h1c = h1b + (size_t)(t & 1) * H1N;
        const u16* h2p = h2b + (size_t)((t - 1) & 1) * H1N;
        const u16* src = (kw < 2) ? h1c : h2p;       // kw0,1: W_ih2·h1; kw2,3: W_hh2·h2
        const u16* bbase = src + ((size_t)((kw & 1) * 64 + q) * 128 +
                                  bh * 64 + l16) * 8;
        f32x4 acc[2][4];
#pragma unroll
        for (int mt = 0; mt < 2; ++mt)
#pragma unroll
          for (int n = 0; n < 4; ++n) acc[mt][n] = (f32x4){0, 0, 0, 0};
        mac_ring_cc<16, 0, 16>(A2[0], A2[1], bbase, acc);

        if (kw >= 2) red_write(red + (bh * 2 + kw - 2) * 2048, acc, lane);
        __syncthreads();
        if (kw < 2)  red_add(red + (bh * 2 + kw) * 2048, acc, lane);
        if (kw == 1) red_write(red + (bh * 2 + 1) * 2048, acc, lane);
        __syncthreads();
        if (kw == 0) {
          red_add(red + (bh * 2 + 1) * 2048, acc, lane);
          lstm_tail(acc, bsv0, bsv1, cst, smem, bh, lane, q, l16,
                    h2b + (size_t)(t & 1) * H1N + (size_t)j * HCH);
        }
      }
      gbar(bar, (unsigned)p + 1u);
    }
  }
}

extern "C" void kernel_launch(void* const* d_in, const int* in_sizes, int n_in,
                              void* d_out, int out_size, void* d_ws, size_t ws_size,
                              hipStream_t stream)
{
  const float* x    = (const float*)d_in[0];
  const float* Wih1 = (const float*)d_in[1];
  const float* bih1 = (const float*)d_in[2];
  const float* Whh1 = (const float*)d_in[3];
  const float* bhh1 = (const float*)d_in[4];
  const float* Wih2 = (const float*)d_in[5];
  const float* bih2 = (const float*)d_in[6];
  const float* Whh2 = (const float*)d_in[7];
  const float* bhh2 = (const float*)d_in[8];
  const float* W1   = (const float*)d_in[9];
  const float* b1   = (const float*)d_in[10];
  const float* W2   = (const float*)d_in[11];
  const float* b2   = (const float*)d_in[12];
  float* out = (float*)d_out;
  (void)in_sizes; (void)n_in; (void)out_size;

  char* ws = (char*)d_ws;
  size_t off = 0;
  auto alloc = [&](size_t n) { char* p = ws + off; off += (n + 255) & ~(size_t)255; return p; };
  u16* W1i   = (u16*)alloc((size_t)4096 * K1P * 2);     // 10.49 MB
  u16* W2i   = (u16*)alloc((size_t)4096 * K2 * 2);      // 16.78 MB
  u16* W1m   = (u16*)alloc((size_t)MM * HH * 2);
  u16* W2m   = (u16*)alloc((size_t)VV * MM * 2);
  u16* Xb    = (u16*)alloc((size_t)TT * 20 * BB * 8 * 2);  // 41.94 MB
  float* bs1 = (float*)alloc(4096 * 4);
  float* bs2 = (float*)alloc(4096 * 4);
  // zeroed region (contiguous): h1b (+pad for zero-A overrun tiles), h2b, midb, bar
  u16* h1b   = (u16*)alloc(2 * (size_t)H1N * 2 + 32768);
  u16* h2b   = (u16*)alloc(2 * (size_t)H1N * 2);
  u16* midb  = (u16*)alloc(2 * (size_t)MIDN * 2);
  unsigned* bar = (unsigned*)alloc(4096);
  if (ws_size < off) return;  // ~71 MB required

  conv_w1i<<<4096, 256, 0, stream>>>(Wih1, Whh1, bih1, bhh1, W1i, bs1);
  conv_w2i<<<4096, 256, 0, stream>>>(Wih2, Whh2, bih2, bhh2, W2i, bs2);
  conv_mlpw<<<576, 256, 0, stream>>>(W1, W2, W1m, W2m);
  conv_x<<<TT * 20, 128, 0, stream>>>(x, Xb);
  {
    int n16 = (int)((2 * (size_t)H1N * 2 + 32768 + 2 * (size_t)H1N * 2 +
                     2 * (size_t)MIDN * 2 + 4096) / 16);
    zero_ws<<<(n16 + 255) / 256, 256, 0, stream>>>((uint4*)h1b, n16);
  }

  (void)hipFuncSetAttribute((const void*)fused_lstm,
                            hipFuncAttributeMaxDynamicSharedMemorySize, LDSZ);
  void* args[] = { (void*)&W1i, (void*)&W2i, (void*)&W1m, (void*)&W2m,
                   (void*)&Xb, (void*)&h1b, (void*)&h2b, (void*)&midb,
                   (void*)&bs1, (void*)&bs2, (void*)&b1, (void*)&b2,
                   (void*)&out, (void*)&bar };
  hipError_t err = hipLaunchCooperativeKernel((const void*)fused_lstm,
                                              dim3(256), dim3(512), args, LDSZ, stream);
  if (err != hipSuccess) {
    fused_lstm<<<dim3(256), dim3(512), LDSZ, stream>>>(W1i, W2i, W1m, W2m, Xb,
                                                       h1b, h2b, midb, bs1, bs2,
                                                       b1, b2, out, bar);
  }
}

// Round 2
// 15972.490 us; speedup vs baseline: 1.2909x; 1.0117x over previous
//
#include <hip/hip_runtime.h>
#include <cstdint>
#include <cstddef>

// Problem dims
#define TT   1024
#define BB   128
#define FEAT 138
#define FPAD 160            // x K-pad (20 chunks of 8)
#define HH   1024
#define VV   128
#define MM   128
#define K1   1184           // FPAD + HH
#define K1P  1280           // padded to 40 k-tiles of 32 (tiles 37..39 zero-A, SKIPPED)
#define K2   2048           // 64 k-tiles
#define HCH  1024           // u16 per k-chunk of h-like buffers: 128 b x 8 k
#define H1N  131072         // u16 per h buffer (128 chunks)
#define MIDN 16384          // u16 per mid buffer (16 chunks)
#define PKM1 1032           // LDS row stride, MLP W1 slice
#define PKM2 136            // LDS row stride, MLP W2 slice
// LDS layout (bytes)
#define OFF_RED 0           // 32 KB: split-k reduction staging (4 regions x 8 KB)
#define OFF_WM  32768       // 33 KB: MLP weight slice
#define OFF_H   65792       // 2 KB: h epilogue transpose staging (2 x 1 KB)
#define OFF_M   67840       // 1 KB: MLP epilogue staging
#define LDSZ    68864

typedef __bf16 bf16x8 __attribute__((ext_vector_type(8)));
typedef float  f32x4  __attribute__((ext_vector_type(4)));
typedef unsigned short u16;

__device__ __forceinline__ u16 f2bf(float f) {  // RNE float->bf16
  uint32_t u = __float_as_uint(f);
  u += 0x7fffu + ((u >> 16) & 1u);
  return (u16)(u >> 16);
}
__device__ __forceinline__ float sigm(float x) { return 1.0f / (1.0f + __expf(-x)); }
__device__ __forceinline__ float tanh_(float x) {
  float e = __expf(-2.0f * fabsf(x));
  float t = (1.0f - e) / (1.0f + e);
  return x < 0.0f ? -t : t;
}

// Cross-block h/mid STORES: sc0sc1 write-through (relaxed agent atomics) —
// data lands at L3 coherent point, nothing dirty in any L2, so the release
// side of the grid barrier needs only vmcnt(0), no buffer_wbl2.
__device__ __forceinline__ void stcc16(u16* p, uint4 v) {
  unsigned long long* p64 = (unsigned long long*)p;
  unsigned long long lo = ((unsigned long long)v.y << 32) | v.x;
  unsigned long long hi = ((unsigned long long)v.w << 32) | v.z;
  __hip_atomic_store(p64,     lo, __ATOMIC_RELAXED, __HIP_MEMORY_SCOPE_AGENT);
  __hip_atomic_store(p64 + 1, hi, __ATOMIC_RELAXED, __HIP_MEMORY_SCOPE_AGENT);
}

// ---------------- prep kernels ----------------
// Gate-interleaved rows r' = hc*4 + gate, K-major; W1 padded to K1P with zeros.
__global__ void conv_w1i(const float* __restrict__ Wih, const float* __restrict__ Whh,
                         const float* __restrict__ bi, const float* __restrict__ bh,
                         u16* __restrict__ dst, float* __restrict__ bsum) {
  int rp = blockIdx.x;                 // 4096
  int hc = rp >> 2, g = rp & 3;
  int sr = g * HH + hc;
  if (threadIdx.x == 0) bsum[rp] = bi[sr] + bh[sr];
  for (int k = threadIdx.x; k < K1P; k += 256) {
    float v = 0.0f;
    if (k < FPAD)    v = (k < FEAT) ? Wih[(size_t)sr * FEAT + k] : 0.0f;
    else if (k < K1) v = Whh[(size_t)sr * HH + (k - FPAD)];
    dst[(size_t)rp * K1P + k] = f2bf(v);
  }
}
__global__ void conv_w2i(const float* __restrict__ Wih, const float* __restrict__ Whh,
                         const float* __restrict__ bi, const float* __restrict__ bh,
                         u16* __restrict__ dst, float* __restrict__ bsum) {
  int rp = blockIdx.x;
  int hc = rp >> 2, g = rp & 3;
  int sr = g * HH + hc;
  if (threadIdx.x == 0) bsum[rp] = bi[sr] + bh[sr];
  for (int k = threadIdx.x; k < K2; k += 256) {
    float v = (k < HH) ? Wih[(size_t)sr * HH + k] : Whh[(size_t)sr * HH + (k - HH)];
    dst[(size_t)rp * K2 + k] = f2bf(v);
  }
}
__global__ void conv_mlpw(const float* __restrict__ W1, const float* __restrict__ W2,
                          u16* __restrict__ A, u16* __restrict__ Bm) {
  int i = blockIdx.x * 256 + threadIdx.x;          // 576*256 covers 131072+16384
  if (i < MM * HH) A[i] = f2bf(W1[i]);
  else {
    int j = i - MM * HH;
    if (j < VV * MM) Bm[j] = f2bf(W2[j]);
  }
}
// x -> chunked bf16 [t][20 c][128 b][8 k]
__global__ void conv_x(const float* __restrict__ x, u16* __restrict__ Xb) {
  int blk = blockIdx.x;                 // TT*20
  int t = blk / 20, c = blk % 20;
  int b = threadIdx.x;
  if (b >= BB) return;
  const float* src = x + ((size_t)t * BB + b) * FEAT;
  u16 v[8];
#pragma unroll
  for (int e = 0; e < 8; ++e) {
    int col = c * 8 + e;
    v[e] = (col < FEAT) ? f2bf(src[col]) : (u16)0;
  }
  *(uint4*)(Xb + (((size_t)t * 20 + c) * BB + b) * 8) = *(uint4*)v;
}
__global__ void zero_ws(uint4* __restrict__ p, int n16) {
  int i = blockIdx.x * 256 + threadIdx.x;
  if (i < n16) p[i] = uint4{0, 0, 0, 0};
}

// ---------------- fused persistent kernel helpers ----------------

// Consumer loads are PLAIN cached loads (L2-served); freshness is guaranteed
// by the per-phase acquire fence (buffer_inv) inside gbar.
__device__ __forceinline__ void mac_step(const bf16x8& a0, const bf16x8& a1,
                                         const u16* __restrict__ bptr,
                                         f32x4 (&acc)[2][4]) {
  bf16x8 Bf[4];
#pragma unroll
  for (int n = 0; n < 4; ++n) Bf[n] = *(const bf16x8*)(bptr + n * 128);
#pragma unroll
  for (int n = 0; n < 4; ++n) {
    acc[0][n] = __builtin_amdgcn_mfma_f32_16x16x32_bf16(a0, Bf[n], acc[0][n], 0, 0, 0);
    acc[1][n] = __builtin_amdgcn_mfma_f32_16x16x32_bf16(a1, Bf[n], acc[1][n], 0, 0, 0);
  }
}

__device__ __forceinline__ void red_write(float* __restrict__ rg,
                                          const f32x4 (&acc)[2][4], int lane) {
#pragma unroll
  for (int mt = 0; mt < 2; ++mt)
#pragma unroll
    for (int n = 0; n < 4; ++n)
      *(f32x4*)(rg + (mt * 4 + n) * 256 + lane * 4) = acc[mt][n];
}
__device__ __forceinline__ void red_add(const float* __restrict__ rg,
                                        f32x4 (&acc)[2][4], int lane) {
#pragma unroll
  for (int mt = 0; mt < 2; ++mt)
#pragma unroll
    for (int n = 0; n < 4; ++n)
      acc[mt][n] += *(const f32x4*)(rg + (mt * 4 + n) * 256 + lane * 4);
}

// kw0 epilogue: gates -> c,h (registers), LDS transpose, coalesced h chunk write.
__device__ __forceinline__ void lstm_tail(f32x4 (&acc)[2][4], const f32x4& bsv0,
                                          const f32x4& bsv1, float (&cst)[2][4],
                                          char* smem, int bh, int lane, int q, int l16,
                                          u16* __restrict__ houtChunk) {
  u16* st = (u16*)(smem + OFF_H) + bh * 512;
#pragma unroll
  for (int mt = 0; mt < 2; ++mt) {
    const f32x4 bsv = mt ? bsv1 : bsv0;
#pragma unroll
    for (int n = 0; n < 4; ++n) {
      float iv = sigm(acc[mt][n][0] + bsv[0]);
      float fv = sigm(acc[mt][n][1] + bsv[1]);
      float gv = tanh_(acc[mt][n][2] + bsv[2]);
      float ov = sigm(acc[mt][n][3] + bsv[3]);
      float c = fv * cst[mt][n] + iv * gv;
      cst[mt][n] = c;
      st[(n * 16 + l16) * 8 + mt * 4 + q] = f2bf(ov * tanh_(c));
    }
  }
  uint4 hv4 = *(uint4*)((u16*)(smem + OFF_H) + bh * 512 + lane * 8);
  stcc16(houtChunk + ((size_t)bh * 64 + lane) * 8, hv4);   // write-through past L2
}

// Grid barrier. Release = per-wave vmcnt(0) (sc0sc1 stores already at L3).
// Acquire = ONE fence (buffer_inv: CU-L1 + XCD-L2 invalidate) per block per
// phase, issued BETWEEN arrive and the release poll so the walk hides under
// the spin. Safety: during phase q, same-XCD blocks only load parities
// {h1:(q-1)&1, h2:q&1, mid:(q-1)&1}, disjoint from the sets phase q+1 reads
// {h1:q&1, h2:(q+1)&1, mid:q&1} — no stale refill is possible in the window.
// (Requires the kw3 zero-A overrun tiles to be skipped — done below.)
__device__ __forceinline__ void gbar(unsigned* __restrict__ bar, unsigned g) {
  asm volatile("s_waitcnt vmcnt(0)" ::: "memory");  // release: stores acked at L3
  __syncthreads();
  if (threadIdx.x == 0) {
    unsigned v = __hip_atomic_fetch_add(&bar[(blockIdx.x & 7) * 16], 1u,
                                        __ATOMIC_RELAXED, __HIP_MEMORY_SCOPE_AGENT);
    if (v == 32u * g - 1u) {
      unsigned w = __hip_atomic_fetch_add(&bar[128], 1u,
                                          __ATOMIC_RELAXED, __HIP_MEMORY_SCOPE_AGENT);
      if (w == 8u * g - 1u)
        __hip_atomic_store(&bar[144], g, __ATOMIC_RELAXED, __HIP_MEMORY_SCOPE_AGENT);
    }
    __builtin_amdgcn_fence(__ATOMIC_ACQUIRE, "agent");   // L1+L2 inv, under spin
    while (__hip_atomic_load(&bar[144], __ATOMIC_RELAXED,
                             __HIP_MEMORY_SCOPE_AGENT) < g)
      __builtin_amdgcn_s_sleep(8);
  }
  __syncthreads();
}

// 256 blocks x 512 thr. Blocks [0,128): LSTM1 slice j (+ MLP); [128,256): LSTM2.
// Waves: w = bh*4 + kw; kw = k-split (4-way), bh = batch-half (2-way).
// Weights register-resident; split-k partials reduced via LDS tree (2 rounds).
__global__ __launch_bounds__(512, 2) void fused_lstm(
    const u16* __restrict__ W1i, const u16* __restrict__ W2i,
    const u16* __restrict__ W1m, const u16* __restrict__ W2m,
    const u16* __restrict__ Xb, u16* __restrict__ h1b, u16* __restrict__ h2b,
    u16* __restrict__ midb,
    const float* __restrict__ bs1, const float* __restrict__ bs2,
    const float* __restrict__ bm1, const float* __restrict__ bm2,
    float* __restrict__ out, unsigned* __restrict__ bar)
{
  extern __shared__ char smem[];
  const int tid = threadIdx.x, bid = blockIdx.x;
  const int w = tid >> 6, lane = tid & 63, q = lane >> 4, l16 = lane & 15;
  const int kw = w & 3, bh = w >> 2;
  const bool isL1 = bid < 128;
  const int j = isL1 ? bid : bid - 128;          // hc-slice: hc = j*8 .. j*8+8
  float* red = (float*)(smem + OFF_RED);
  u16* Wm = (u16*)(smem + OFF_WM);

  float cst[2][4] = {{0, 0, 0, 0}, {0, 0, 0, 0}};   // kw0: persistent cell state
  f32x4 bsv0 = {0, 0, 0, 0}, bsv1 = {0, 0, 0, 0};
  if (kw == 0) {
    const float* bs = isL1 ? bs1 : bs2;
    bsv0 = *(const f32x4*)(bs + (j * 8 + q) * 4);
    bsv1 = *(const f32x4*)(bs + (j * 8 + 4 + q) * 4);
  }

  if (isL1) {
    // ---- register-resident A: 2 m-tiles x 10 k-tiles (tiles kw*10..kw*10+9) ----
    bf16x8 A1[2][10];
#pragma unroll
    for (int mt = 0; mt < 2; ++mt)
#pragma unroll
      for (int s = 0; s < 10; ++s)
        A1[mt][s] = *(const bf16x8*)(W1i + (size_t)(j * 32 + mt * 16 + l16) * K1P +
                                     (size_t)(kw * 10 + s) * 32 + q * 8);
    // MLP weight slice -> LDS
    if (j < 64) {
      int m0 = (j & 7) * 16;
      for (int i = tid; i < 16 * 128; i += 512) {
        int r = i >> 7, c8 = i & 127;
        *(uint4*)(Wm + r * PKM1 + c8 * 8) =
            *(const uint4*)(W1m + ((size_t)(m0 + r)) * HH + c8 * 8);
      }
    } else {
      int v0 = ((j - 64) & 7) * 16;
      for (int i = tid; i < 16 * 16; i += 512) {
        int r = i >> 4, c8 = i & 15;
        *(uint4*)(Wm + r * PKM2 + c8 * 8) =
            *(const uint4*)(W2m + ((size_t)(v0 + r)) * MM + c8 * 8);
      }
    }
    f32x4 bmv = {0, 0, 0, 0};
    if (w == 3) {
      if (j < 64) bmv = *(const f32x4*)(bm1 + (j & 7) * 16 + q * 4);
      else        bmv = *(const f32x4*)(bm2 + ((j - 64) & 7) * 16 + q * 4);
    }
    __syncthreads();

    for (int p = 0; p < TT + 3; ++p) {
      const bool act = p < TT;
      if (act) {                        // ---- LSTM1, t = p ----
        const u16* h1p = h1b + (size_t)((p - 1) & 1) * H1N;
        f32x4 acc[2][4];
#pragma unroll
        for (int mt = 0; mt < 2; ++mt)
#pragma unroll
          for (int n = 0; n < 4; ++n) acc[mt][n] = (f32x4){0, 0, 0, 0};
        if (kw == 0) {                  // tiles 0..4 from x, 5..9 from h1prev
          const u16* bx = Xb + (size_t)p * 20480 +
                          ((size_t)q * 128 + bh * 64 + l16) * 8;
#pragma unroll
          for (int s = 0; s < 5; ++s)
            mac_step(A1[0][s], A1[1][s], bx + (size_t)s * 4096, acc);
          const u16* bp = h1p + ((size_t)q * 128 + bh * 64 + l16) * 8;
#pragma unroll
          for (int s = 0; s < 5; ++s)
            mac_step(A1[0][5 + s], A1[1][5 + s], bp + (size_t)s * 4096, acc);
        } else {                        // tiles kw*10.. from h1prev (lt0 = kw*10-5)
          const u16* bp = h1p + ((size_t)((kw * 10 - 5) * 4 + q) * 128 +
                                 bh * 64 + l16) * 8;
          if (kw == 3) {                // tiles 30..36 only; 37..39 are zero-A
#pragma unroll
            for (int s = 0; s < 7; ++s)
              mac_step(A1[0][s], A1[1][s], bp + (size_t)s * 4096, acc);
          } else {
#pragma unroll
            for (int s = 0; s < 10; ++s)
              mac_step(A1[0][s], A1[1][s], bp + (size_t)s * 4096, acc);
          }
        }
        // split-k tree reduction
        if (kw >= 2) red_write(red + (bh * 2 + kw - 2) * 2048, acc, lane);
        __syncthreads();
        if (kw < 2)  red_add(red + (bh * 2 + kw) * 2048, acc, lane);
        if (kw == 1) red_write(red + (bh * 2 + 1) * 2048, acc, lane);
        __syncthreads();
        if (kw == 0) {
          red_add(red + (bh * 2 + 1) * 2048, acc, lane);
          lstm_tail(acc, bsv0, bsv1, cst, smem, bh, lane, q, l16,
                    h1b + (size_t)(p & 1) * H1N + (size_t)j * HCH);
        }
      }
      if (w == 3) {                     // ---- MLP (wave 3 of L1 blocks) ----
        if (j < 64) {
          if (p >= 2 && p <= TT + 1) {  // mid, t = p-2
            int jm = j & 7, jb = j >> 3;
            const u16* bsrc = h2b + (size_t)(p & 1) * H1N + q * HCH +
                              (jb * 16 + l16) * 8;
            const u16* am = Wm + l16 * PKM1 + q * 8;
            f32x4 acc = {0, 0, 0, 0};
#pragma unroll 4
            for (int s = 0; s < 32; ++s) {
              bf16x8 bf = *(const bf16x8*)(bsrc + (size_t)s * 4096);
              bf16x8 af = *(const bf16x8*)(am + s * 32);
              acc = __builtin_amdgcn_mfma_f32_16x16x32_bf16(af, bf, acc, 0, 0, 0);
            }
            const float SC = 1.0507009873554804934193349852946f;
            const float AL = 1.6732632423543772848170429916717f;
            u16* st16 = (u16*)(smem + OFF_M);
#pragma unroll
            for (int r = 0; r < 4; ++r) {
              float v = acc[r] + bmv[r];
              v = v > 0.0f ? SC * v : SC * AL * (__expf(v) - 1.0f);
              st16[l16 * 16 + q * 4 + r] = f2bf(v);
            }
            if (lane < 16) {
              uint4 v0 = *(uint4*)(st16 + lane * 16);
              uint4 v1 = *(uint4*)(st16 + lane * 16 + 8);
              u16* mc = midb + (size_t)(p & 1) * MIDN;
              stcc16(mc + (size_t)(2 * jm) * HCH + (jb * 16 + lane) * 8, v0);
              stcc16(mc + (size_t)(2 * jm + 1) * HCH + (jb * 16 + lane) * 8, v1);
            }
          }
        } else if (p >= 3) {            // out, t = p-3
          int jj = j - 64, jv = jj & 7, jb = jj >> 3;
          const u16* bsrc = midb + (size_t)((p - 3) & 1) * MIDN + q * HCH +
                            (jb * 16 + l16) * 8;
          const u16* am = Wm + l16 * PKM2 + q * 8;
          f32x4 acc = {0, 0, 0, 0};
#pragma unroll
          for (int s = 0; s < 4; ++s) {
            bf16x8 bf = *(const bf16x8*)(bsrc + (size_t)s * 4096);
            bf16x8 af = *(const bf16x8*)(am + s * 32);
            acc = __builtin_amdgcn_mfma_f32_16x16x32_bf16(af, bf, acc, 0, 0, 0);
          }
          float* stf = (float*)(smem + OFF_M);
#pragma unroll
          for (int r = 0; r < 4; ++r) stf[l16 * 16 + q * 4 + r] = acc[r] + bmv[r];
          if (lane < 16) {
            float* orow = out + ((size_t)(p - 3) * BB + jb * 16 + lane) * VV + jv * 16;
            uint4* s4 = (uint4*)(stf + lane * 16);
            *(uint4*)(orow + 0)  = s4[0];
            *(uint4*)(orow + 4)  = s4[1];
            *(uint4*)(orow + 8)  = s4[2];
            *(uint4*)(orow + 12) = s4[3];
          }
        }
      }
      gbar(bar, (unsigned)p + 1u);
    }
  } else {
    // ---- LSTM2: register A: 2 m-tiles x 16 k-tiles (tiles kw*16..kw*16+15) ----
    bf16x8 A2[2][16];
#pragma unroll
    for (int mt = 0; mt < 2; ++mt)
#pragma unroll
      for (int s = 0; s < 16; ++s)
        A2[mt][s] = *(const bf16x8*)(W2i + (size_t)(j * 32 + mt * 16 + l16) * K2 +
                                     (size_t)(kw * 16 + s) * 32 + q * 8);

    for (int p = 0; p < TT + 3; ++p) {
      const bool act = (p >= 1 && p <= TT);
      if (act) {                        // ---- LSTM2, t = p-1 ----
        const int t = p - 1;
        const u16* h1c = h1b + (size_t)(t & 1) * H1N;
        const u16* h2p = h2b + (size_t)((t - 1) & 1) * H1N;
        const u16* src = (kw < 2) ? h1c : h2p;       // kw0,1: W_ih2·h1; kw2,3: W_hh2·h2
        const u16* bbase = src + ((size_t)((kw & 1) * 64 + q) * 128 +
                                  bh * 64 + l16) * 8;
        f32x4 acc[2][4];
#pragma unroll
        for (int mt = 0; mt < 2; ++mt)
#pragma unroll
          for (int n = 0; n < 4; ++n) acc[mt][n] = (f32x4){0, 0, 0, 0};
#pragma unroll
        for (int s = 0; s < 16; ++s)
          mac_step(A2[0][s], A2[1][s], bbase + (size_t)s * 4096, acc);

        if (kw >= 2) red_write(red + (bh * 2 + kw - 2) * 2048, acc, lane);
        __syncthreads();
        if (kw < 2)  red_add(red + (bh * 2 + kw) * 2048, acc, lane);
        if (kw == 1) red_write(red + (bh * 2 + 1) * 2048, acc, lane);
        __syncthreads();
        if (kw == 0) {
          red_add(red + (bh * 2 + 1) * 2048, acc, lane);
          lstm_tail(acc, bsv0, bsv1, cst, smem, bh, lane, q, l16,
                    h2b + (size_t)(t & 1) * H1N + (size_t)j * HCH);
        }
      }
      gbar(bar, (unsigned)p + 1u);
    }
  }
}

extern "C" void kernel_launch(void* const* d_in, const int* in_sizes, int n_in,
                              void* d_out, int out_size, void* d_ws, size_t ws_size,
                              hipStream_t stream)
{
  const float* x    = (const float*)d_in[0];
  const float* Wih1 = (const float*)d_in[1];
  const float* bih1 = (const float*)d_in[2];
  const float* Whh1 = (const float*)d_in[3];
  const float* bhh1 = (const float*)d_in[4];
  const float* Wih2 = (const float*)d_in[5];
  const float* bih2 = (const float*)d_in[6];
  const float* Whh2 = (const float*)d_in[7];
  const float* bhh2 = (const float*)d_in[8];
  const float* W1   = (const float*)d_in[9];
  const float* b1   = (const float*)d_in[10];
  const float* W2   = (const float*)d_in[11];
  const float* b2   = (const float*)d_in[12];
  float* out = (float*)d_out;
  (void)in_sizes; (void)n_in; (void)out_size;

  char* ws = (char*)d_ws;
  size_t off = 0;
  auto alloc = [&](size_t n) { char* p = ws + off; off += (n + 255) & ~(size_t)255; return p; };
  u16* W1i   = (u16*)alloc((size_t)4096 * K1P * 2);     // 10.49 MB
  u16* W2i   = (u16*)alloc((size_t)4096 * K2 * 2);      // 16.78 MB
  u16* W1m   = (u16*)alloc((size_t)MM * HH * 2);
  u16* W2m   = (u16*)alloc((size_t)VV * MM * 2);
  u16* Xb    = (u16*)alloc((size_t)TT * 20 * BB * 8 * 2);  // 41.94 MB
  float* bs1 = (float*)alloc(4096 * 4);
  float* bs2 = (float*)alloc(4096 * 4);
  // zeroed region (contiguous): h1b (+pad), h2b, midb, bar
  u16* h1b   = (u16*)alloc(2 * (size_t)H1N * 2 + 32768);
  u16* h2b   = (u16*)alloc(2 * (size_t)H1N * 2);
  u16* midb  = (u16*)alloc(2 * (size_t)MIDN * 2);
  unsigned* bar = (unsigned*)alloc(4096);
  if (ws_size < off) return;  // ~71 MB required

  conv_w1i<<<4096, 256, 0, stream>>>(Wih1, Whh1, bih1, bhh1, W1i, bs1);
  conv_w2i<<<4096, 256, 0, stream>>>(Wih2, Whh2, bih2, bhh2, W2i, bs2);
  conv_mlpw<<<576, 256, 0, stream>>>(W1, W2, W1m, W2m);
  conv_x<<<TT * 20, 128, 0, stream>>>(x, Xb);
  {
    int n16 = (int)((2 * (size_t)H1N * 2 + 32768 + 2 * (size_t)H1N * 2 +
                     2 * (size_t)MIDN * 2 + 4096) / 16);
    zero_ws<<<(n16 + 255) / 256, 256, 0, stream>>>((uint4*)h1b, n16);
  }

  (void)hipFuncSetAttribute((const void*)fused_lstm,
                            hipFuncAttributeMaxDynamicSharedMemorySize, LDSZ);
  void* args[] = { (void*)&W1i, (void*)&W2i, (void*)&W1m, (void*)&W2m,
                   (void*)&Xb, (void*)&h1b, (void*)&h2b, (void*)&midb,
                   (void*)&bs1, (void*)&bs2, (void*)&b1, (void*)&b2,
                   (void*)&out, (void*)&bar };
  hipError_t err = hipLaunchCooperativeKernel((const void*)fused_lstm,
                                              dim3(256), dim3(512), args, LDSZ, stream);
  if (err != hipSuccess) {
    fused_lstm<<<dim3(256), dim3(512), LDSZ, stream>>>(W1i, W2i, W1m, W2m, Xb,
                                                       h1b, h2b, midb, bs1, bs2,
                                                       b1, b2, out, bar);
  }
}

// Round 3
// 14720.587 us; speedup vs baseline: 1.4007x; 1.0850x over previous
//
#include <hip/hip_runtime.h>
#include <cstdint>
#include <cstddef>

// Problem dims
#define TT   1024
#define BB   128
#define FEAT 138
#define FPAD 160            // x K-pad (20 chunks of 8)
#define HH   1024
#define VV   128
#define MM   128
#define K1   1184           // FPAD + HH
#define K1P  1280           // padded to 40 k-tiles of 32 (tiles 37..39 zero-A, SKIPPED)
#define K2   2048           // 64 k-tiles
#define HCH  1024           // u16 per k-chunk of h-like buffers: 128 b x 8 k
#define H1N  131072         // u16 per h buffer (128 chunks)
#define MIDN 16384          // u16 per mid buffer (16 chunks)
#define PKM1 1032           // LDS row stride, MLP W1 slice (in-loop fallback)
#define PKM2 136            // LDS row stride, MLP W2 slice (in-loop fallback)
// LDS layout (bytes)
#define OFF_RED 0           // 32 KB: split-k reduction staging (4 regions x 8 KB)
#define OFF_WM  32768       // 33 KB: MLP weight slice (fallback)
#define OFF_H   65792       // 2 KB: h epilogue transpose staging (2 x 1 KB)
#define OFF_M   67840       // 1 KB: MLP epilogue staging (fallback)
#define LDSZ    68864

typedef __bf16 bf16x8 __attribute__((ext_vector_type(8)));
typedef float  f32x4  __attribute__((ext_vector_type(4)));
typedef unsigned short u16;

__device__ __forceinline__ u16 f2bf(float f) {  // RNE float->bf16
  uint32_t u = __float_as_uint(f);
  u += 0x7fffu + ((u >> 16) & 1u);
  return (u16)(u >> 16);
}
__device__ __forceinline__ float sigm(float x) { return 1.0f / (1.0f + __expf(-x)); }
__device__ __forceinline__ float tanh_(float x) {
  float e = __expf(-2.0f * fabsf(x));
  float t = (1.0f - e) / (1.0f + e);
  return x < 0.0f ? -t : t;
}

// Cross-block h/mid STORES: sc0sc1 write-through (relaxed agent atomics) —
// data lands at L3 coherent point, nothing dirty in any L2, so the release
// side of the grid barrier needs only vmcnt(0), no buffer_wbl2.
__device__ __forceinline__ void stcc16(u16* p, uint4 v) {
  unsigned long long* p64 = (unsigned long long*)p;
  unsigned long long lo = ((unsigned long long)v.y << 32) | v.x;
  unsigned long long hi = ((unsigned long long)v.w << 32) | v.z;
  __hip_atomic_store(p64,     lo, __ATOMIC_RELAXED, __HIP_MEMORY_SCOPE_AGENT);
  __hip_atomic_store(p64 + 1, hi, __ATOMIC_RELAXED, __HIP_MEMORY_SCOPE_AGENT);
}

// ---------------- prep kernels ----------------
__global__ void conv_w1i(const float* __restrict__ Wih, const float* __restrict__ Whh,
                         const float* __restrict__ bi, const float* __restrict__ bh,
                         u16* __restrict__ dst, float* __restrict__ bsum) {
  int rp = blockIdx.x;                 // 4096
  int hc = rp >> 2, g = rp & 3;
  int sr = g * HH + hc;
  if (threadIdx.x == 0) bsum[rp] = bi[sr] + bh[sr];
  for (int k = threadIdx.x; k < K1P; k += 256) {
    float v = 0.0f;
    if (k < FPAD)    v = (k < FEAT) ? Wih[(size_t)sr * FEAT + k] : 0.0f;
    else if (k < K1) v = Whh[(size_t)sr * HH + (k - FPAD)];
    dst[(size_t)rp * K1P + k] = f2bf(v);
  }
}
__global__ void conv_w2i(const float* __restrict__ Wih, const float* __restrict__ Whh,
                         const float* __restrict__ bi, const float* __restrict__ bh,
                         u16* __restrict__ dst, float* __restrict__ bsum) {
  int rp = blockIdx.x;
  int hc = rp >> 2, g = rp & 3;
  int sr = g * HH + hc;
  if (threadIdx.x == 0) bsum[rp] = bi[sr] + bh[sr];
  for (int k = threadIdx.x; k < K2; k += 256) {
    float v = (k < HH) ? Wih[(size_t)sr * HH + k] : Whh[(size_t)sr * HH + (k - HH)];
    dst[(size_t)rp * K2 + k] = f2bf(v);
  }
}
__global__ void conv_mlpw(const float* __restrict__ W1, const float* __restrict__ W2,
                          u16* __restrict__ A, u16* __restrict__ Bm) {
  int i = blockIdx.x * 256 + threadIdx.x;          // 576*256 covers 131072+16384
  if (i < MM * HH) A[i] = f2bf(W1[i]);
  else {
    int j = i - MM * HH;
    if (j < VV * MM) Bm[j] = f2bf(W2[j]);
  }
}
// x -> chunked bf16 [t][20 c][128 b][8 k]
__global__ void conv_x(const float* __restrict__ x, u16* __restrict__ Xb) {
  int blk = blockIdx.x;                 // TT*20
  int t = blk / 20, c = blk % 20;
  int b = threadIdx.x;
  if (b >= BB) return;
  const float* src = x + ((size_t)t * BB + b) * FEAT;
  u16 v[8];
#pragma unroll
  for (int e = 0; e < 8; ++e) {
    int col = c * 8 + e;
    v[e] = (col < FEAT) ? f2bf(src[col]) : (u16)0;
  }
  *(uint4*)(Xb + (((size_t)t * 20 + c) * BB + b) * 8) = *(uint4*)v;
}
__global__ void zero_ws(uint4* __restrict__ p, int n16) {
  int i = blockIdx.x * 256 + threadIdx.x;
  if (i < n16) p[i] = uint4{0, 0, 0, 0};
}

// ---------------- fused persistent kernel helpers ----------------

__device__ __forceinline__ void mfma_tile(const bf16x8& a0, const bf16x8& a1,
                                          const bf16x8 (&B)[4], f32x4 (&acc)[2][4]) {
#pragma unroll
  for (int n = 0; n < 4; ++n) {
    acc[0][n] = __builtin_amdgcn_mfma_f32_16x16x32_bf16(a0, B[n], acc[0][n], 0, 0, 0);
    acc[1][n] = __builtin_amdgcn_mfma_f32_16x16x32_bf16(a1, B[n], acc[1][n], 0, 0, 0);
  }
}
__device__ __forceinline__ void ld_tile(const u16* __restrict__ p, bf16x8 (&B)[4]) {
#pragma unroll
  for (int n = 0; n < 4; ++n) B[n] = *(const bf16x8*)(p + n * 128);
}
// Depth-4 software-pipelined k-tile ring, PLAIN loads (compiler waitcnts),
// static indexing only (s % D fully unrolled).
template<int NT, int OFS, int NA>
__device__ __forceinline__ void mac_ring(const bf16x8 (&A0)[NA], const bf16x8 (&A1)[NA],
                                         const u16* __restrict__ bp,
                                         f32x4 (&acc)[2][4]) {
  constexpr int D = NT < 4 ? NT : 4;
  bf16x8 Bq[D][4];
#pragma unroll
  for (int s = 0; s < D; ++s) ld_tile(bp + (size_t)s * 4096, Bq[s]);
#pragma unroll
  for (int s = 0; s < NT; ++s) {
    mfma_tile(A0[OFS + s], A1[OFS + s], Bq[s % D], acc);
    if (s + D < NT) ld_tile(bp + (size_t)(s + D) * 4096, Bq[s % D]);
  }
}
// Fallback MLP helper (in-loop variant)
__device__ __forceinline__ void mac_step(const bf16x8& a0, const bf16x8& a1,
                                         const u16* __restrict__ bptr,
                                         f32x4 (&acc)[2][4]) {
  bf16x8 Bf[4];
  ld_tile(bptr, Bf);
  mfma_tile(a0, a1, Bf, acc);
}

__device__ __forceinline__ void red_write(float* __restrict__ rg,
                                          const f32x4 (&acc)[2][4], int lane) {
#pragma unroll
  for (int mt = 0; mt < 2; ++mt)
#pragma unroll
    for (int n = 0; n < 4; ++n)
      *(f32x4*)(rg + (mt * 4 + n) * 256 + lane * 4) = acc[mt][n];
}
__device__ __forceinline__ void red_add(const float* __restrict__ rg,
                                        f32x4 (&acc)[2][4], int lane) {
#pragma unroll
  for (int mt = 0; mt < 2; ++mt)
#pragma unroll
    for (int n = 0; n < 4; ++n)
      acc[mt][n] += *(const f32x4*)(rg + (mt * 4 + n) * 256 + lane * 4);
}

// kw0 epilogue: gates -> c,h (registers), LDS transpose, coalesced h chunk write.
__device__ __forceinline__ void lstm_tail(f32x4 (&acc)[2][4], const f32x4& bsv0,
                                          const f32x4& bsv1, float (&cst)[2][4],
                                          char* smem, int bh, int lane, int q, int l16,
                                          u16* __restrict__ houtChunk) {
  u16* st = (u16*)(smem + OFF_H) + bh * 512;
#pragma unroll
  for (int mt = 0; mt < 2; ++mt) {
    const f32x4 bsv = mt ? bsv1 : bsv0;
#pragma unroll
    for (int n = 0; n < 4; ++n) {
      float iv = sigm(acc[mt][n][0] + bsv[0]);
      float fv = sigm(acc[mt][n][1] + bsv[1]);
      float gv = tanh_(acc[mt][n][2] + bsv[2]);
      float ov = sigm(acc[mt][n][3] + bsv[3]);
      float c = fv * cst[mt][n] + iv * gv;
      cst[mt][n] = c;
      st[(n * 16 + l16) * 8 + mt * 4 + q] = f2bf(ov * tanh_(c));
    }
  }
  uint4 hv4 = *(uint4*)((u16*)(smem + OFF_H) + bh * 512 + lane * 8);
  stcc16(houtChunk + ((size_t)bh * 64 + lane) * 8, hv4);   // write-through past L2
}

// Grid barrier. Release = per-wave vmcnt(0) (sc0sc1 stores already at L3).
// Acquire = ONE buffer_inv per block per phase under the spin. Safety: phase q
// readers touch parities/slabs disjoint from phase q+1's, and h2hist slabs are
// write-once, so a racing inv can only force a refetch of FRESH data.
__device__ __forceinline__ void gbar(unsigned* __restrict__ bar, unsigned g) {
  asm volatile("s_waitcnt vmcnt(0)" ::: "memory");  // release: stores acked at L3
  __syncthreads();
  if (threadIdx.x == 0) {
    unsigned v = __hip_atomic_fetch_add(&bar[(blockIdx.x & 7) * 16], 1u,
                                        __ATOMIC_RELAXED, __HIP_MEMORY_SCOPE_AGENT);
    if (v == 32u * g - 1u) {
      unsigned w = __hip_atomic_fetch_add(&bar[128], 1u,
                                          __ATOMIC_RELAXED, __HIP_MEMORY_SCOPE_AGENT);
      if (w == 8u * g - 1u)
        __hip_atomic_store(&bar[144], g, __ATOMIC_RELAXED, __HIP_MEMORY_SCOPE_AGENT);
    }
    __builtin_amdgcn_fence(__ATOMIC_ACQUIRE, "agent");   // L1+L2 inv, under spin
    while (__hip_atomic_load(&bar[144], __ATOMIC_RELAXED,
                             __HIP_MEMORY_SCOPE_AGENT) < g)
      __builtin_amdgcn_s_sleep(1);
  }
  __syncthreads();
}

// MODE 0: in-loop MLP (fallback, == R2 behavior). MODE 1: MLP deferred to
// post-pass; LSTM2 writes h2 history slabs (write-once) instead of parity.
// 256 blocks x 512 thr. Blocks [0,128): LSTM1 slice j; [128,256): LSTM2.
template<int MODE>
__global__ __launch_bounds__(512, 2) void fused_lstm(
    const u16* __restrict__ W1i, const u16* __restrict__ W2i,
    const u16* __restrict__ W1m, const u16* __restrict__ W2m,
    const u16* __restrict__ Xb, u16* __restrict__ h1b, u16* __restrict__ h2b,
    u16* __restrict__ h2h, u16* __restrict__ midb,
    const float* __restrict__ bs1, const float* __restrict__ bs2,
    const float* __restrict__ bm1, const float* __restrict__ bm2,
    float* __restrict__ out, unsigned* __restrict__ bar)
{
  extern __shared__ char smem[];
  const int tid = threadIdx.x, bid = blockIdx.x;
  const int w = tid >> 6, lane = tid & 63, q = lane >> 4, l16 = lane & 15;
  const int kw = w & 3, bh = w >> 2;
  const bool isL1 = bid < 128;
  const int j = isL1 ? bid : bid - 128;          // hc-slice: hc = j*8 .. j*8+8
  float* red = (float*)(smem + OFF_RED);
  u16* Wm = (u16*)(smem + OFF_WM);
  const int PEND = MODE ? (TT + 1) : (TT + 3);

  float cst[2][4] = {{0, 0, 0, 0}, {0, 0, 0, 0}};   // kw0: persistent cell state
  f32x4 bsv0 = {0, 0, 0, 0}, bsv1 = {0, 0, 0, 0};
  if (kw == 0) {
    const float* bs = isL1 ? bs1 : bs2;
    bsv0 = *(const f32x4*)(bs + (j * 8 + q) * 4);
    bsv1 = *(const f32x4*)(bs + (j * 8 + 4 + q) * 4);
  }

  if (isL1) {
    // ---- register-resident A: 2 m-tiles x 10 k-tiles ----
    bf16x8 A1[2][10];
#pragma unroll
    for (int mt = 0; mt < 2; ++mt)
#pragma unroll
      for (int s = 0; s < 10; ++s)
        A1[mt][s] = *(const bf16x8*)(W1i + (size_t)(j * 32 + mt * 16 + l16) * K1P +
                                     (size_t)(kw * 10 + s) * 32 + q * 8);
    f32x4 bmv = {0, 0, 0, 0};
    if constexpr (MODE == 0) {
      // MLP weight slice -> LDS (fallback only)
      if (j < 64) {
        int m0 = (j & 7) * 16;
        for (int i = tid; i < 16 * 128; i += 512) {
          int r = i >> 7, c8 = i & 127;
          *(uint4*)(Wm + r * PKM1 + c8 * 8) =
              *(const uint4*)(W1m + ((size_t)(m0 + r)) * HH + c8 * 8);
        }
      } else {
        int v0 = ((j - 64) & 7) * 16;
        for (int i = tid; i < 16 * 16; i += 512) {
          int r = i >> 4, c8 = i & 15;
          *(uint4*)(Wm + r * PKM2 + c8 * 8) =
              *(const uint4*)(W2m + ((size_t)(v0 + r)) * MM + c8 * 8);
        }
      }
      if (w == 3) {
        if (j < 64) bmv = *(const f32x4*)(bm1 + (j & 7) * 16 + q * 4);
        else        bmv = *(const f32x4*)(bm2 + ((j - 64) & 7) * 16 + q * 4);
      }
      __syncthreads();
    }

    for (int p = 0; p < PEND; ++p) {
      const bool act = p < TT;
      if (act) {                        // ---- LSTM1, t = p ----
        const u16* h1p = h1b + (size_t)((p - 1) & 1) * H1N;
        f32x4 acc[2][4];
#pragma unroll
        for (int mt = 0; mt < 2; ++mt)
#pragma unroll
          for (int n = 0; n < 4; ++n) acc[mt][n] = (f32x4){0, 0, 0, 0};
        if (kw == 0) {                  // tiles 0..4 from x, 5..9 from h1prev
          const u16* bx = Xb + (size_t)p * 20480 +
                          ((size_t)q * 128 + bh * 64 + l16) * 8;
          mac_ring<5, 0, 10>(A1[0], A1[1], bx, acc);
          const u16* bp = h1p + ((size_t)q * 128 + bh * 64 + l16) * 8;
          mac_ring<5, 5, 10>(A1[0], A1[1], bp, acc);
        } else {                        // tiles kw*10.. from h1prev (lt0 = kw*10-5)
          const u16* bp = h1p + ((size_t)((kw * 10 - 5) * 4 + q) * 128 +
                                 bh * 64 + l16) * 8;
          if (kw == 3) mac_ring<7, 0, 10>(A1[0], A1[1], bp, acc);   // 37..39 zero-A
          else         mac_ring<10, 0, 10>(A1[0], A1[1], bp, acc);
        }
        // split-k tree reduction
        if (kw >= 2) red_write(red + (bh * 2 + kw - 2) * 2048, acc, lane);
        __syncthreads();
        if (kw < 2)  red_add(red + (bh * 2 + kw) * 2048, acc, lane);
        if (kw == 1) red_write(red + (bh * 2 + 1) * 2048, acc, lane);
        __syncthreads();
        if (kw == 0) {
          red_add(red + (bh * 2 + 1) * 2048, acc, lane);
          lstm_tail(acc, bsv0, bsv1, cst, smem, bh, lane, q, l16,
                    h1b + (size_t)(p & 1) * H1N + (size_t)j * HCH);
        }
      }
      if constexpr (MODE == 0) {
        if (w == 3) {                   // ---- in-loop MLP (fallback) ----
          if (j < 64) {
            if (p >= 2 && p <= TT + 1) {  // mid, t = p-2
              int jm = j & 7, jb = j >> 3;
              const u16* bsrc = h2b + (size_t)(p & 1) * H1N + q * HCH +
                                (jb * 16 + l16) * 8;
              const u16* am = Wm + l16 * PKM1 + q * 8;
              f32x4 acc = {0, 0, 0, 0};
#pragma unroll 4
              for (int s = 0; s < 32; ++s) {
                bf16x8 bf = *(const bf16x8*)(bsrc + (size_t)s * 4096);
                bf16x8 af = *(const bf16x8*)(am + s * 32);
                acc = __builtin_amdgcn_mfma_f32_16x16x32_bf16(af, bf, acc, 0, 0, 0);
              }
              const float SC = 1.0507009873554804934193349852946f;
              const float AL = 1.6732632423543772848170429916717f;
              u16* st16 = (u16*)(smem + OFF_M);
#pragma unroll
              for (int r = 0; r < 4; ++r) {
                float v = acc[r] + bmv[r];
                v = v > 0.0f ? SC * v : SC * AL * (__expf(v) - 1.0f);
                st16[l16 * 16 + q * 4 + r] = f2bf(v);
              }
              if (lane < 16) {
                uint4 v0 = *(uint4*)(st16 + lane * 16);
                uint4 v1 = *(uint4*)(st16 + lane * 16 + 8);
                u16* mc = midb + (size_t)(p & 1) * MIDN;
                stcc16(mc + (size_t)(2 * jm) * HCH + (jb * 16 + lane) * 8, v0);
                stcc16(mc + (size_t)(2 * jm + 1) * HCH + (jb * 16 + lane) * 8, v1);
              }
            }
          } else if (p >= 3) {          // out, t = p-3
            int jj = j - 64, jv = jj & 7, jb = jj >> 3;
            const u16* bsrc = midb + (size_t)((p - 3) & 1) * MIDN + q * HCH +
                              (jb * 16 + l16) * 8;
            const u16* am = Wm + l16 * PKM2 + q * 8;
            f32x4 acc = {0, 0, 0, 0};
#pragma unroll
            for (int s = 0; s < 4; ++s) {
              bf16x8 bf = *(const bf16x8*)(bsrc + (size_t)s * 4096);
              bf16x8 af = *(const bf16x8*)(am + s * 32);
              acc = __builtin_amdgcn_mfma_f32_16x16x32_bf16(af, bf, acc, 0, 0, 0);
            }
            float* stf = (float*)(smem + OFF_M);
#pragma unroll
            for (int r = 0; r < 4; ++r) stf[l16 * 16 + q * 4 + r] = acc[r] + bmv[r];
            if (lane < 16) {
              float* orow = out + ((size_t)(p - 3) * BB + jb * 16 + lane) * VV + jv * 16;
              uint4* s4 = (uint4*)(stf + lane * 16);
              *(uint4*)(orow + 0)  = s4[0];
              *(uint4*)(orow + 4)  = s4[1];
              *(uint4*)(orow + 8)  = s4[2];
              *(uint4*)(orow + 12) = s4[3];
            }
          }
        }
      }
      gbar(bar, (unsigned)p + 1u);
    }
  } else {
    // ---- LSTM2: register A: 2 m-tiles x 16 k-tiles ----
    bf16x8 A2[2][16];
#pragma unroll
    for (int mt = 0; mt < 2; ++mt)
#pragma unroll
      for (int s = 0; s < 16; ++s)
        A2[mt][s] = *(const bf16x8*)(W2i + (size_t)(j * 32 + mt * 16 + l16) * K2 +
                                     (size_t)(kw * 16 + s) * 32 + q * 8);

    for (int p = 0; p < PEND; ++p) {
      const bool act = (p >= 1 && p <= TT);
      if (act) {                        // ---- LSTM2, t = p-1 ----
        const int t = p - 1;
        const u16* h1c = h1b + (size_t)(t & 1) * H1N;
        const u16* h2p = MODE ? (h2h + (size_t)t * H1N)            // slab t = h2(t-1)
                              : (h2b + (size_t)((t - 1) & 1) * H1N);
        const u16* src = (kw < 2) ? h1c : h2p;       // kw0,1: W_ih2·h1; kw2,3: W_hh2·h2
        const u16* bbase = src + ((size_t)((kw & 1) * 64 + q) * 128 +
                                  bh * 64 + l16) * 8;
        f32x4 acc[2][4];
#pragma unroll
        for (int mt = 0; mt < 2; ++mt)
#pragma unroll
          for (int n = 0; n < 4; ++n) acc[mt][n] = (f32x4){0, 0, 0, 0};
        mac_ring<16, 0, 16>(A2[0], A2[1], bbase, acc);

        if (kw >= 2) red_write(red + (bh * 2 + kw - 2) * 2048, acc, lane);
        __syncthreads();
        if (kw < 2)  red_add(red + (bh * 2 + kw) * 2048, acc, lane);
        if (kw == 1) red_write(red + (bh * 2 + 1) * 2048, acc, lane);
        __syncthreads();
        if (kw == 0) {
          red_add(red + (bh * 2 + 1) * 2048, acc, lane);
          u16* dst = MODE ? (h2h + (size_t)(t + 1) * H1N + (size_t)j * HCH)
                          : (h2b + (size_t)(t & 1) * H1N + (size_t)j * HCH);
          lstm_tail(acc, bsv0, bsv1, cst, smem, bh, lane, q, l16, dst);
        }
      }
      gbar(bar, (unsigned)p + 1u);
    }
  }
}

// ---------------- post-pass MLP head (MODE 1) ----------------
// One block per t: mid = selu(h2(t)·W1^T + b1) -> LDS; out = mid·W2^T + b2.
__global__ __launch_bounds__(256) void mlp_head(
    const u16* __restrict__ W1m, const u16* __restrict__ W2m,
    const u16* __restrict__ h2h, const float* __restrict__ b1,
    const float* __restrict__ b2, float* __restrict__ out)
{
  __shared__ u16 midl[16 * 128 * 8];     // 32 KB: [chunk][b][8k]
  const int tid = threadIdx.x, t = blockIdx.x;
  const int wid = tid >> 6, lane = tid & 63, q = lane >> 4, l16 = lane & 15;
  const u16* h2t = h2h + (size_t)(t + 1) * H1N;   // slab t+1 = h2(t)
  const int mbase = wid * 32;

  f32x4 acc[2][8];
#pragma unroll
  for (int a = 0; a < 2; ++a)
#pragma unroll
    for (int n = 0; n < 8; ++n) acc[a][n] = (f32x4){0, 0, 0, 0};
#pragma unroll 2
  for (int kc = 0; kc < 32; ++kc) {
    bf16x8 a0 = *(const bf16x8*)(W1m + (size_t)(mbase + l16) * HH + kc * 32 + q * 8);
    bf16x8 a1 = *(const bf16x8*)(W1m + (size_t)(mbase + 16 + l16) * HH + kc * 32 + q * 8);
    const u16* bp = h2t + (size_t)(kc * 4 + q) * 1024 + l16 * 8;
#pragma unroll
    for (int n = 0; n < 8; ++n) {
      bf16x8 bf = *(const bf16x8*)(bp + n * 128);
      acc[0][n] = __builtin_amdgcn_mfma_f32_16x16x32_bf16(a0, bf, acc[0][n], 0, 0, 0);
      acc[1][n] = __builtin_amdgcn_mfma_f32_16x16x32_bf16(a1, bf, acc[1][n], 0, 0, 0);
    }
  }
  const float SC = 1.0507009873554804934193349852946f;
  const float AL = 1.6732632423543772848170429916717f;
  f32x4 bm0 = *(const f32x4*)(b1 + mbase + q * 4);
  f32x4 bm1v = *(const f32x4*)(b1 + mbase + 16 + q * 4);
#pragma unroll
  for (int mt = 0; mt < 2; ++mt) {
    const f32x4 bm = mt ? bm1v : bm0;
    const int m0 = mbase + mt * 16 + q * 4;
#pragma unroll
    for (int n = 0; n < 8; ++n) {
      const int b = n * 16 + l16;
#pragma unroll
      for (int r = 0; r < 4; ++r) {
        float v = acc[mt][n][r] + bm[r];
        v = v > 0.0f ? SC * v : SC * AL * (__expf(v) - 1.0f);
        int mm = m0 + r;
        midl[(mm >> 3) * 1024 + b * 8 + (mm & 7)] = f2bf(v);
      }
    }
  }
  __syncthreads();
  f32x4 acc2[2][8];
#pragma unroll
  for (int a = 0; a < 2; ++a)
#pragma unroll
    for (int n = 0; n < 8; ++n) acc2[a][n] = (f32x4){0, 0, 0, 0};
#pragma unroll
  for (int kc = 0; kc < 4; ++kc) {
    bf16x8 a0 = *(const bf16x8*)(W2m + (size_t)(mbase + l16) * MM + kc * 32 + q * 8);
    bf16x8 a1 = *(const bf16x8*)(W2m + (size_t)(mbase + 16 + l16) * MM + kc * 32 + q * 8);
    const u16* bp = midl + (kc * 4 + q) * 1024 + l16 * 8;
#pragma unroll
    for (int n = 0; n < 8; ++n) {
      bf16x8 bf = *(const bf16x8*)(bp + n * 128);
      acc2[0][n] = __builtin_amdgcn_mfma_f32_16x16x32_bf16(a0, bf, acc2[0][n], 0, 0, 0);
      acc2[1][n] = __builtin_amdgcn_mfma_f32_16x16x32_bf16(a1, bf, acc2[1][n], 0, 0, 0);
    }
  }
  f32x4 c0 = *(const f32x4*)(b2 + mbase + q * 4);
  f32x4 c1 = *(const f32x4*)(b2 + mbase + 16 + q * 4);
  float* ot = out + (size_t)t * BB * VV;
#pragma unroll
  for (int mt = 0; mt < 2; ++mt)
#pragma unroll
    for (int n = 0; n < 8; ++n) {
      f32x4 v = acc2[mt][n] + (mt ? c1 : c0);
      *(f32x4*)(ot + (size_t)(n * 16 + l16) * VV + mbase + mt * 16 + q * 4) = v;
    }
}

extern "C" void kernel_launch(void* const* d_in, const int* in_sizes, int n_in,
                              void* d_out, int out_size, void* d_ws, size_t ws_size,
                              hipStream_t stream)
{
  const float* x    = (const float*)d_in[0];
  const float* Wih1 = (const float*)d_in[1];
  const float* bih1 = (const float*)d_in[2];
  const float* Whh1 = (const float*)d_in[3];
  const float* bhh1 = (const float*)d_in[4];
  const float* Wih2 = (const float*)d_in[5];
  const float* bih2 = (const float*)d_in[6];
  const float* Whh2 = (const float*)d_in[7];
  const float* bhh2 = (const float*)d_in[8];
  const float* W1   = (const float*)d_in[9];
  const float* b1   = (const float*)d_in[10];
  const float* W2   = (const float*)d_in[11];
  const float* b2   = (const float*)d_in[12];
  float* out = (float*)d_out;
  (void)in_sizes; (void)n_in; (void)out_size;

  char* ws = (char*)d_ws;
  size_t off = 0;
  auto alloc = [&](size_t n) { char* p = ws + off; off += (n + 255) & ~(size_t)255; return p; };
  u16* W1i   = (u16*)alloc((size_t)4096 * K1P * 2);     // 10.49 MB
  u16* W2i   = (u16*)alloc((size_t)4096 * K2 * 2);      // 16.78 MB
  u16* W1m   = (u16*)alloc((size_t)MM * HH * 2);
  u16* W2m   = (u16*)alloc((size_t)VV * MM * 2);
  u16* Xb    = (u16*)alloc((size_t)TT * 20 * BB * 8 * 2);  // 41.94 MB
  float* bs1 = (float*)alloc(4096 * 4);
  float* bs2 = (float*)alloc(4096 * 4);
  // zeroed region (contiguous): h1b (+pad), h2b, midb, bar
  u16* h1b   = (u16*)alloc(2 * (size_t)H1N * 2 + 32768);
  u16* h2b   = (u16*)alloc(2 * (size_t)H1N * 2);
  u16* midb  = (u16*)alloc(2 * (size_t)MIDN * 2);
  unsigned* bar = (unsigned*)alloc(4096);
  size_t off_base = off;                         // ~71 MB
  u16* h2h   = (u16*)alloc((size_t)(TT + 1) * H1N * 2);   // 268.7 MB (MODE 1)
  const bool postMLP = ws_size >= off;
  if (ws_size < off_base) return;

  conv_w1i<<<4096, 256, 0, stream>>>(Wih1, Whh1, bih1, bhh1, W1i, bs1);
  conv_w2i<<<4096, 256, 0, stream>>>(Wih2, Whh2, bih2, bhh2, W2i, bs2);
  conv_mlpw<<<576, 256, 0, stream>>>(W1, W2, W1m, W2m);
  conv_x<<<TT * 20, 128, 0, stream>>>(x, Xb);
  {
    int n16 = (int)((2 * (size_t)H1N * 2 + 32768 + 2 * (size_t)H1N * 2 +
                     2 * (size_t)MIDN * 2 + 4096) / 16);
    zero_ws<<<(n16 + 255) / 256, 256, 0, stream>>>((uint4*)h1b, n16);
  }
  if (postMLP) {   // zero h2 history slab 0 (= h2(-1))
    zero_ws<<<(H1N * 2 / 16 + 255) / 256, 256, 0, stream>>>((uint4*)h2h, H1N * 2 / 16);
  }

  using KFn = void (*)(const u16*, const u16*, const u16*, const u16*, const u16*,
                       u16*, u16*, u16*, u16*, const float*, const float*,
                       const float*, const float*, float*, unsigned*);
  KFn fp = postMLP ? (KFn)fused_lstm<1> : (KFn)fused_lstm<0>;
  (void)hipFuncSetAttribute((const void*)fp,
                            hipFuncAttributeMaxDynamicSharedMemorySize, LDSZ);
  void* args[] = { (void*)&W1i, (void*)&W2i, (void*)&W1m, (void*)&W2m,
                   (void*)&Xb, (void*)&h1b, (void*)&h2b, (void*)&h2h, (void*)&midb,
                   (void*)&bs1, (void*)&bs2, (void*)&b1, (void*)&b2,
                   (void*)&out, (void*)&bar };
  hipError_t err = hipLaunchCooperativeKernel((const void*)fp,
                                              dim3(256), dim3(512), args, LDSZ, stream);
  if (err != hipSuccess) {
    if (postMLP)
      fused_lstm<1><<<dim3(256), dim3(512), LDSZ, stream>>>(
          W1i, W2i, W1m, W2m, Xb, h1b, h2b, h2h, midb, bs1, bs2, b1, b2, out, bar);
    else
      fused_lstm<0><<<dim3(256), dim3(512), LDSZ, stream>>>(
          W1i, W2i, W1m, W2m, Xb, h1b, h2b, h2h, midb, bs1, bs2, b1, b2, out, bar);
  }
  if (postMLP) {
    mlp_head<<<dim3(TT), dim3(256), 0, stream>>>(W1m, W2m, h2h, b1, b2, out);
  }
}